// Round 9
// baseline (7446.132 us; speedup 1.0000x reference)
//
#include <hip/hip_runtime.h>
#include <hip/hip_bf16.h>

#define T_STEPS 512
#define BATCH   128
#define IN      512
#define HID     512
#define KTOT    1024   // IN + HID fused
#define BT      16     // batch rows per block
#define JT      16     // hidden units per block
#define NBT     8      // batch groups
#define NJT     32     // blocks per group
#define BH      (BATCH * HID)
#define HROW    1024   // u32 per hseq row (32 tiles x 32 u32; 16 useful + 16 pad each)

typedef __attribute__((ext_vector_type(8))) short bf16x8;
typedef __attribute__((ext_vector_type(4))) float f32x4;
typedef __attribute__((ext_vector_type(4))) unsigned int u32x4;

static __device__ __forceinline__ unsigned short f2bf(float f) {
    unsigned u = __float_as_uint(f);
    unsigned r = (u + 0x7FFFu + ((u >> 16) & 1u)) >> 16;   // RNE, finite inputs only
    return (unsigned short)r;
}
static __device__ __forceinline__ ushort4 pack4(float4 v) {
    ushort4 b4;
    b4.x = f2bf(v.x); b4.y = f2bf(v.y); b4.z = f2bf(v.z); b4.w = f2bf(v.w);
    return b4;
}
static __device__ __forceinline__ float tanh_fast(float x) {
    return 1.f - 2.f * __builtin_amdgcn_rcpf(1.f + __expf(2.f * x));
}
static __device__ __forceinline__ bool vld4(u32x4 v, unsigned tgtw) {
    return ((v[0] & 0xFFFF0000u) == tgtw) & ((v[1] & 0xFFFF0000u) == tgtw) &
           ((v[2] & 0xFFFF0000u) == tgtw) & ((v[3] & 0xFFFF0000u) == tgtw);
}

// ---- prep: fuse W_ih|W_hh into bf16 [2048][1024], bias = b_ih + b_hh ----
__global__ void prep_kernel(const float* __restrict__ W_ih, const float* __restrict__ W_hh,
                            const float* __restrict__ b_ih, const float* __restrict__ b_hh,
                            unsigned short* __restrict__ Wc, float* __restrict__ bias) {
    int idx = blockIdx.x * blockDim.x + threadIdx.x;   // 0 .. 2048*256-1 float4 granules
    int row = idx >> 8;
    int kq  = idx & 255;
    const float* src = (kq < 128) ? (W_ih + (size_t)row * IN + kq * 4)
                                  : (W_hh + (size_t)row * HID + (kq - 128) * 4);
    float4 v = *(const float4*)src;
    *(ushort4*)(Wc + (size_t)row * KTOT + kq * 4) = pack4(v);
    if (idx < 4 * HID) bias[idx] = b_ih[idx] + b_hh[idx];
}

// ---- persistent LSTM kernel ----
__global__ __launch_bounds__(256, 2) void lstm_kernel(
    const float* __restrict__ xin, const float* __restrict__ h0,
    const float* __restrict__ c0, const unsigned short* __restrict__ Wc,
    const float* __restrict__ bias, float* __restrict__ out,
    unsigned* __restrict__ hseq)   // [2][BATCH][HROW] u32: (seq<<16)|bf16(h), 128B line per (row, jt)
{
    const int tid  = threadIdx.x;
    const int bid  = blockIdx.x;
    const int bt   = bid & 7;        // batch group
    const int jt   = bid >> 3;       // j tile 0..31
    const int wv   = tid >> 6;       // wave id
    const int lane = tid & 63;
    const int ln15 = lane & 15;
    const int khi  = lane >> 4;

    // 2 x-slots [0,16K),[16K,32K); 2 h-slots [32K,48K),[48K,64K)
    __shared__ __align__(16) unsigned char smem[65536];

    const int gown = ln15 & 3;              // lane's gate (0=i,1=f,2=g,3=o)
    const int jj   = ln15 >> 2;             // j sub-index
    const int jcol = jt * JT + wv * 4 + jj; // global hidden unit
    const int wrow_idx = gown * HID + jcol;

    // B-fragments (gate-interleaved columns) in VGPRs
    bf16x8 wfrag[32];
    {
        const unsigned short* wrow = Wc + (size_t)wrow_idx * KTOT;
        #pragma unroll
        for (int kk = 0; kk < 32; ++kk)
            wfrag[kk] = *(const bf16x8*)(wrow + kk * 32 + khi * 8);
    }
    const float biasv = bias[wrow_idx];

    // cell state: creg[R] = c(b = khi*4+R, jcol), 4x redundant across gate lanes
    float creg[4];
    #pragma unroll
    for (int R = 0; R < 4; ++R)
        creg[R] = c0[(size_t)(bt * BT + khi * 4 + R) * HID + jcol];

    const unsigned swz = (unsigned)((ln15 & 7) << 4);
    const int xrow0 = tid >> 7;          // 0..1
    const int xcol4 = tid & 127;         // float4 granule within 1024-wide row

    // poll mapping: quarter (wv,khi) owns row wv*4+khi.
    // inst q, lane ln15 -> tile tau = 4q + (ln15>>2), within-tile u32 = (ln15&3)*4
    const int prow  = wv * 4 + khi;
    const unsigned rsw = (unsigned)((prow & 7) << 4);
    const int lsub  = ln15 >> 2;         // 0..3 tile sub-index
    const int lofs  = ln15 & 3;          // 0..3 quad within tile

    // ---- prologue: stage x0 -> xslot0, h0 -> hslot0; prefetch x1 ----
    #pragma unroll
    for (int i = 0; i < 8; ++i) {
        int row = xrow0 + 2 * i;
        unsigned off = ((unsigned)(xcol4 * 8)) ^ ((unsigned)((row & 7) << 4));
        float4 vx = *(const float4*)(xin + (size_t)(bt * BT + row) * IN + xcol4 * 4);
        *(ushort4*)(smem + (size_t)row * 1024 + off) = pack4(vx);
        float4 vh = *(const float4*)(h0 + (size_t)(bt * BT + row) * HID + xcol4 * 4);
        *(ushort4*)(smem + 32768 + (size_t)row * 1024 + off) = pack4(vh);
    }
    float4 xr[8];
    #pragma unroll
    for (int i = 0; i < 8; ++i)
        xr[i] = *(const float4*)(xin + (size_t)1 * (BATCH * IN)
                                     + (size_t)(bt * BT + xrow0 + 2 * i) * IN + xcol4 * 4);
    __syncthreads();

    bool fastmode = true;   // per-wave adaptive scope; flips (permanently) to MALL on timeout

    #pragma unroll 1
    for (int t = 0; t < T_STEPS; ++t) {
        // ---- MFMA: 16 x-steps + 16 h-steps from slots (t&1) ----
        const unsigned xbase = (unsigned)(t & 1) * 16384u;
        const unsigned hbase = 32768u + (unsigned)(t & 1) * 16384u;
        f32x4 acc0 = {biasv, biasv, biasv, biasv};
        f32x4 acc1 = {0.f, 0.f, 0.f, 0.f};
        const unsigned char* xrow_p = smem + xbase + (size_t)ln15 * 1024;
        const unsigned char* hrow_p = smem + hbase + (size_t)ln15 * 1024;
        #pragma unroll
        for (int kk = 0; kk < 16; ++kk) {
            unsigned off = ((unsigned)(kk * 64 + khi * 16)) ^ swz;
            bf16x8 af = *(const bf16x8*)(xrow_p + off);
            if (kk & 1) acc1 = __builtin_amdgcn_mfma_f32_16x16x32_bf16(af, wfrag[kk], acc1, 0, 0, 0);
            else        acc0 = __builtin_amdgcn_mfma_f32_16x16x32_bf16(af, wfrag[kk], acc0, 0, 0, 0);
        }
        #pragma unroll
        for (int kk = 16; kk < 32; ++kk) {
            unsigned off = ((unsigned)((kk - 16) * 64 + khi * 16)) ^ swz;
            bf16x8 af = *(const bf16x8*)(hrow_p + off);
            if (kk & 1) acc1 = __builtin_amdgcn_mfma_f32_16x16x32_bf16(af, wfrag[kk], acc1, 0, 0, 0);
            else        acc0 = __builtin_amdgcn_mfma_f32_16x16x32_bf16(af, wfrag[kk], acc0, 0, 0, 0);
        }
        f32x4 accs = acc0 + acc1;

        // ---- activation + intra-wave gate exchange + cell update ----
        float hR[4];
        const int srcbase = lane & 0x3C;
        #pragma unroll
        for (int R = 0; R < 4; ++R) {
            float x = accs[R];
            bool isg = (gown == 2);
            float e = __expf(isg ? 2.f * x : -x);
            float r = __builtin_amdgcn_rcpf(1.f + e);
            float a = isg ? 1.f - 2.f * r : r;
            float vi = __shfl(a, srcbase + 0);
            float vf = __shfl(a, srcbase + 1);
            float vg = __shfl(a, srcbase + 2);
            float vo = __shfl(a, srcbase + 3);
            float c = vf * creg[R] + vi * vg;
            creg[R] = c;
            hR[R] = vo * tanh_fast(c);
        }

        if (t < T_STEPS - 1) {
            // ---- publish h_t: dual-scope self-validating u32 (line-exclusive tile slot) ----
            const size_t slotu = (size_t)(t & 1) * (BATCH * HROW);
            #pragma unroll
            for (int R = 0; R < 4; ++R) {
                if (gown == R) {
                    unsigned w = ((unsigned)(t + 1) << 16) | (unsigned)f2bf(hR[R]);
                    unsigned* hp = hseq + slotu
                                 + (size_t)(bt * BT + khi * 4 + R) * HROW
                                 + jt * 32 + wv * 4 + jj;
                    asm volatile("global_store_dword %0, %1, off sc0"     :: "v"(hp), "v"(w) : "memory");
                    asm volatile("global_store_dword %0, %1, off sc0 sc1" :: "v"(hp), "v"(w) : "memory");
                }
            }

            // ---- out store (off critical chain) ----
            #pragma unroll
            for (int R = 0; R < 4; ++R) {
                if (gown == R)
                    out[(size_t)t * BH + (size_t)(bt * BT + khi * 4 + R) * HID + jcol] = hR[R];
            }

            // ---- stage x_{t+1} (old xr) -> x slot (t+1)&1 ----
            {
                unsigned xnb = (unsigned)((t + 1) & 1) * 16384u;
                #pragma unroll
                for (int i = 0; i < 8; ++i) {
                    int row = xrow0 + 2 * i;
                    unsigned off = ((unsigned)(xcol4 * 8)) ^ ((unsigned)((row & 7) << 4));
                    *(ushort4*)(smem + xnb + (size_t)row * 1024 + off) = pack4(xr[i]);
                }
            }

            // ---- one-shot self-validating h load + bounded adaptive retry ----
            const unsigned* pp = hseq + slotu + (size_t)(bt * BT + prow) * HROW
                                      + lsub * 32 + lofs * 4;
            const unsigned tgtw = (unsigned)(t + 1) << 16;
            u32x4 hv0, hv1, hv2, hv3, hv4, hv5, hv6, hv7;
            if (fastmode) asm volatile(
                "global_load_dwordx4 %0, %8, off offset:0 sc0\n\t"
                "global_load_dwordx4 %1, %8, off offset:512 sc0\n\t"
                "global_load_dwordx4 %2, %8, off offset:1024 sc0\n\t"
                "global_load_dwordx4 %3, %8, off offset:1536 sc0\n\t"
                "global_load_dwordx4 %4, %8, off offset:2048 sc0\n\t"
                "global_load_dwordx4 %5, %8, off offset:2560 sc0\n\t"
                "global_load_dwordx4 %6, %8, off offset:3072 sc0\n\t"
                "global_load_dwordx4 %7, %8, off offset:3584 sc0\n\t"
                "s_waitcnt vmcnt(0)"
                : "=&v"(hv0), "=&v"(hv1), "=&v"(hv2), "=&v"(hv3),
                  "=&v"(hv4), "=&v"(hv5), "=&v"(hv6), "=&v"(hv7)
                : "v"(pp) : "memory");
            else asm volatile(
                "global_load_dwordx4 %0, %8, off offset:0 sc0 sc1\n\t"
                "global_load_dwordx4 %1, %8, off offset:512 sc0 sc1\n\t"
                "global_load_dwordx4 %2, %8, off offset:1024 sc0 sc1\n\t"
                "global_load_dwordx4 %3, %8, off offset:1536 sc0 sc1\n\t"
                "global_load_dwordx4 %4, %8, off offset:2048 sc0 sc1\n\t"
                "global_load_dwordx4 %5, %8, off offset:2560 sc0 sc1\n\t"
                "global_load_dwordx4 %6, %8, off offset:3072 sc0 sc1\n\t"
                "global_load_dwordx4 %7, %8, off offset:3584 sc0 sc1\n\t"
                "s_waitcnt vmcnt(0)"
                : "=&v"(hv0), "=&v"(hv1), "=&v"(hv2), "=&v"(hv3),
                  "=&v"(hv4), "=&v"(hv5), "=&v"(hv6), "=&v"(hv7)
                : "v"(pp) : "memory");
            bool ok0 = vld4(hv0, tgtw), ok1 = vld4(hv1, tgtw);
            bool ok2 = vld4(hv2, tgtw), ok3 = vld4(hv3, tgtw);
            bool ok4 = vld4(hv4, tgtw), ok5 = vld4(hv5, tgtw);
            bool ok6 = vld4(hv6, tgtw), ok7 = vld4(hv7, tgtw);
            int tries = 0;
            while (__ballot(ok0 & ok1 & ok2 & ok3 & ok4 & ok5 & ok6 & ok7) != ~0ull) {
                ++tries;
                if (fastmode && tries >= 64) {
                    // co-location assumption failed: invalidate stale clean lines, go MALL-authoritative
                    __builtin_amdgcn_fence(__ATOMIC_ACQUIRE, "agent");
                    fastmode = false;
                }
                if (fastmode) {
                    if (!ok0) { asm volatile("global_load_dwordx4 %0, %1, off offset:0 sc0\n\ts_waitcnt vmcnt(0)"    : "=&v"(hv0) : "v"(pp) : "memory"); ok0 = vld4(hv0, tgtw); }
                    if (!ok1) { asm volatile("global_load_dwordx4 %0, %1, off offset:512 sc0\n\ts_waitcnt vmcnt(0)"  : "=&v"(hv1) : "v"(pp) : "memory"); ok1 = vld4(hv1, tgtw); }
                    if (!ok2) { asm volatile("global_load_dwordx4 %0, %1, off offset:1024 sc0\n\ts_waitcnt vmcnt(0)" : "=&v"(hv2) : "v"(pp) : "memory"); ok2 = vld4(hv2, tgtw); }
                    if (!ok3) { asm volatile("global_load_dwordx4 %0, %1, off offset:1536 sc0\n\ts_waitcnt vmcnt(0)" : "=&v"(hv3) : "v"(pp) : "memory"); ok3 = vld4(hv3, tgtw); }
                    if (!ok4) { asm volatile("global_load_dwordx4 %0, %1, off offset:2048 sc0\n\ts_waitcnt vmcnt(0)" : "=&v"(hv4) : "v"(pp) : "memory"); ok4 = vld4(hv4, tgtw); }
                    if (!ok5) { asm volatile("global_load_dwordx4 %0, %1, off offset:2560 sc0\n\ts_waitcnt vmcnt(0)" : "=&v"(hv5) : "v"(pp) : "memory"); ok5 = vld4(hv5, tgtw); }
                    if (!ok6) { asm volatile("global_load_dwordx4 %0, %1, off offset:3072 sc0\n\ts_waitcnt vmcnt(0)" : "=&v"(hv6) : "v"(pp) : "memory"); ok6 = vld4(hv6, tgtw); }
                    if (!ok7) { asm volatile("global_load_dwordx4 %0, %1, off offset:3584 sc0\n\ts_waitcnt vmcnt(0)" : "=&v"(hv7) : "v"(pp) : "memory"); ok7 = vld4(hv7, tgtw); }
                } else {
                    if (!ok0) { asm volatile("global_load_dwordx4 %0, %1, off offset:0 sc0 sc1\n\ts_waitcnt vmcnt(0)"    : "=&v"(hv0) : "v"(pp) : "memory"); ok0 = vld4(hv0, tgtw); }
                    if (!ok1) { asm volatile("global_load_dwordx4 %0, %1, off offset:512 sc0 sc1\n\ts_waitcnt vmcnt(0)"  : "=&v"(hv1) : "v"(pp) : "memory"); ok1 = vld4(hv1, tgtw); }
                    if (!ok2) { asm volatile("global_load_dwordx4 %0, %1, off offset:1024 sc0 sc1\n\ts_waitcnt vmcnt(0)" : "=&v"(hv2) : "v"(pp) : "memory"); ok2 = vld4(hv2, tgtw); }
                    if (!ok3) { asm volatile("global_load_dwordx4 %0, %1, off offset:1536 sc0 sc1\n\ts_waitcnt vmcnt(0)" : "=&v"(hv3) : "v"(pp) : "memory"); ok3 = vld4(hv3, tgtw); }
                    if (!ok4) { asm volatile("global_load_dwordx4 %0, %1, off offset:2048 sc0 sc1\n\ts_waitcnt vmcnt(0)" : "=&v"(hv4) : "v"(pp) : "memory"); ok4 = vld4(hv4, tgtw); }
                    if (!ok5) { asm volatile("global_load_dwordx4 %0, %1, off offset:2560 sc0 sc1\n\ts_waitcnt vmcnt(0)" : "=&v"(hv5) : "v"(pp) : "memory"); ok5 = vld4(hv5, tgtw); }
                    if (!ok6) { asm volatile("global_load_dwordx4 %0, %1, off offset:3072 sc0 sc1\n\ts_waitcnt vmcnt(0)" : "=&v"(hv6) : "v"(pp) : "memory"); ok6 = vld4(hv6, tgtw); }
                    if (!ok7) { asm volatile("global_load_dwordx4 %0, %1, off offset:3584 sc0 sc1\n\ts_waitcnt vmcnt(0)" : "=&v"(hv7) : "v"(pp) : "memory"); ok7 = vld4(hv7, tgtw); }
                }
            }

            // ---- prefetch x_{t+2} (in flight across the barrier) ----
            {
                int tn = (t + 2) & (T_STEPS - 1);
                #pragma unroll
                for (int i = 0; i < 8; ++i)
                    xr[i] = *(const float4*)(xin + (size_t)tn * (BATCH * IN)
                                                 + (size_t)(bt * BT + xrow0 + 2 * i) * IN + xcol4 * 4);
            }

            // ---- pack polled h -> h slot (t+1)&1 ----
            {
                unsigned hnb = 32768u + (unsigned)((t + 1) & 1) * 16384u;
                unsigned wbase = hnb + (unsigned)prow * 1024u;
                const u32x4 hv[8] = {hv0, hv1, hv2, hv3, hv4, hv5, hv6, hv7};
                #pragma unroll
                for (int q = 0; q < 8; ++q) {
                    uint2 pk;
                    pk.x = (hv[q][0] & 0xFFFFu) | (hv[q][1] << 16);
                    pk.y = (hv[q][2] & 0xFFFFu) | (hv[q][3] << 16);
                    unsigned off = ((unsigned)(q * 128 + lsub * 32 + lofs * 8)) ^ rsw;
                    *(uint2*)(smem + wbase + off) = pk;
                }
            }

            asm volatile("s_waitcnt lgkmcnt(0)" ::: "memory");
            __builtin_amdgcn_s_barrier();
        } else {
            // ---- epilogue: out[T-1], hT, cT ----
            #pragma unroll
            for (int R = 0; R < 4; ++R) {
                if (gown == R) {
                    size_t o2 = (size_t)(bt * BT + khi * 4 + R) * HID + jcol;
                    out[(size_t)t * BH + o2] = hR[R];
                    size_t base = (size_t)T_STEPS * BH;
                    out[base + o2] = hR[R];
                    out[base + BH + o2] = creg[R];
                }
            }
        }
    }
}

extern "C" void kernel_launch(void* const* d_in, const int* in_sizes, int n_in,
                              void* d_out, int out_size, void* d_ws, size_t ws_size,
                              hipStream_t stream) {
    const float* input = (const float*)d_in[0];
    const float* h0    = (const float*)d_in[1];
    const float* c0    = (const float*)d_in[2];
    const float* W_ih  = (const float*)d_in[3];
    const float* W_hh  = (const float*)d_in[4];
    const float* b_ih  = (const float*)d_in[5];
    const float* b_hh  = (const float*)d_in[6];
    float* out = (float*)d_out;

    char* ws = (char*)d_ws;
    unsigned* hseq = (unsigned*)ws;                            // 2*128*1024*4 = 1 MB
    float*    bias = (float*)(ws + 1024 * 1024);               // 8 KB
    unsigned short* Wc = (unsigned short*)(ws + 1024 * 1024 + 16 * 1024);  // 4 MB

    hipMemsetAsync(hseq, 0, 2 * BATCH * HROW * sizeof(unsigned), stream);
    prep_kernel<<<2048, 256, 0, stream>>>(W_ih, W_hh, b_ih, b_hh, Wc, bias);
    lstm_kernel<<<NBT * NJT, 256, 0, stream>>>(input, h0, c0, Wc, bias, out, hseq);
}

// Round 11
// 2417.759 us; speedup vs baseline: 3.0798x; 3.0798x over previous
//
#include <hip/hip_runtime.h>
#include <hip/hip_bf16.h>

#define T_STEPS 512
#define BATCH   128
#define IN      512
#define HID     512
#define KTOT    1024   // IN + HID fused
#define BT      16     // batch rows per block
#define JT      16     // hidden units per block
#define NBT     8      // batch groups
#define NJT     32     // blocks per group
#define BH      (BATCH * HID)

typedef __attribute__((ext_vector_type(8))) short bf16x8;
typedef __attribute__((ext_vector_type(4))) float f32x4;
typedef __attribute__((ext_vector_type(4))) unsigned int u32x4;

static __device__ __forceinline__ unsigned short f2bf(float f) {
    unsigned u = __float_as_uint(f);
    unsigned r = (u + 0x7FFFu + ((u >> 16) & 1u)) >> 16;   // RNE, finite inputs only
    return (unsigned short)r;
}
static __device__ __forceinline__ ushort4 pack4(float4 v) {
    ushort4 b4;
    b4.x = f2bf(v.x); b4.y = f2bf(v.y); b4.z = f2bf(v.z); b4.w = f2bf(v.w);
    return b4;
}
static __device__ __forceinline__ float tanh_fast(float x) {
    return 1.f - 2.f * __builtin_amdgcn_rcpf(1.f + __expf(2.f * x));
}
static __device__ __forceinline__ bool vld4(u32x4 v, unsigned tgtw) {
    return ((v[0] & 0xFFFF0000u) == tgtw) & ((v[1] & 0xFFFF0000u) == tgtw) &
           ((v[2] & 0xFFFF0000u) == tgtw) & ((v[3] & 0xFFFF0000u) == tgtw);
}

// ---- prep: fuse W_ih|W_hh into bf16 [2048][1024], bias = b_ih + b_hh ----
__global__ void prep_kernel(const float* __restrict__ W_ih, const float* __restrict__ W_hh,
                            const float* __restrict__ b_ih, const float* __restrict__ b_hh,
                            unsigned short* __restrict__ Wc, float* __restrict__ bias) {
    int idx = blockIdx.x * blockDim.x + threadIdx.x;   // 0 .. 2048*256-1 float4 granules
    int row = idx >> 8;
    int kq  = idx & 255;
    const float* src = (kq < 128) ? (W_ih + (size_t)row * IN + kq * 4)
                                  : (W_hh + (size_t)row * HID + (kq - 128) * 4);
    float4 v = *(const float4*)src;
    *(ushort4*)(Wc + (size_t)row * KTOT + kq * 4) = pack4(v);
    if (idx < 4 * HID) bias[idx] = b_ih[idx] + b_hh[idx];
}

// ---- persistent LSTM kernel ----
__global__ __launch_bounds__(256, 2) void lstm_kernel(
    const float* __restrict__ xin, const float* __restrict__ h0,
    const float* __restrict__ c0, const unsigned short* __restrict__ Wc,
    const float* __restrict__ bias, float* __restrict__ out,
    unsigned* __restrict__ hseq)   // [2][BATCH][HID] u32: (seq<<16)|bf16(h)
{
    const int tid  = threadIdx.x;
    const int bid  = blockIdx.x;
    const int bt   = bid & 7;        // batch group
    const int jt   = bid >> 3;       // j tile 0..31
    const int wv   = tid >> 6;       // wave id
    const int lane = tid & 63;
    const int ln15 = lane & 15;
    const int khi  = lane >> 4;

    // x slot [0,16K); h slots [16K,32K),[32K,48K)
    __shared__ __align__(16) unsigned char smem[49152];

    const int gown = ln15 & 3;              // lane's gate (0=i,1=f,2=g,3=o)
    const int jj   = ln15 >> 2;             // j sub-index
    const int jcol = jt * JT + wv * 4 + jj; // global hidden unit
    const int wrow_idx = gown * HID + jcol;

    // B-fragments (gate-interleaved columns) in VGPRs/AGPRs
    bf16x8 wfrag[32];
    {
        const unsigned short* wrow = Wc + (size_t)wrow_idx * KTOT;
        #pragma unroll
        for (int kk = 0; kk < 32; ++kk)
            wfrag[kk] = *(const bf16x8*)(wrow + kk * 32 + khi * 8);
    }
    const float biasv = bias[wrow_idx];

    // cell state: creg[R] = c(b = khi*4+R, jcol), 4x redundant across gate lanes
    float creg[4];
    #pragma unroll
    for (int R = 0; R < 4; ++R)
        creg[R] = c0[(size_t)(bt * BT + khi * 4 + R) * HID + jcol];

    const unsigned swz = (unsigned)((ln15 & 7) << 4);
    const int xrow0 = tid >> 7;          // 0..1
    const int xcol4 = tid & 127;         // float4 granule within 512-wide fp32 row

    // poll/pack mapping: quarter (wv,khi) owns row prow
    const int prow  = wv * 4 + khi;
    const unsigned rsw = (unsigned)((prow & 7) << 4);

    // ---- prologue: stage x0 -> xslot, h0 -> hslot0; prefetch x1; x-MFMA(step0) ----
    #pragma unroll
    for (int i = 0; i < 8; ++i) {
        int row = xrow0 + 2 * i;
        unsigned off = ((unsigned)(xcol4 * 8)) ^ ((unsigned)((row & 7) << 4));
        float4 vx = *(const float4*)(xin + (size_t)(bt * BT + row) * IN + xcol4 * 4);
        *(ushort4*)(smem + (size_t)row * 1024 + off) = pack4(vx);
        float4 vh = *(const float4*)(h0 + (size_t)(bt * BT + row) * HID + xcol4 * 4);
        *(ushort4*)(smem + 16384 + (size_t)row * 1024 + off) = pack4(vh);
    }
    float4 xr[8];
    #pragma unroll
    for (int i = 0; i < 8; ++i)
        xr[i] = *(const float4*)(xin + (size_t)1 * (BATCH * IN)
                                     + (size_t)(bt * BT + xrow0 + 2 * i) * IN + xcol4 * 4);
    __syncthreads();

    f32x4 acc_x0 = {biasv, biasv, biasv, biasv};
    f32x4 acc_x1 = {0.f, 0.f, 0.f, 0.f};
    {
        const unsigned char* xrow_p = smem + (size_t)ln15 * 1024;
        #pragma unroll
        for (int kk = 0; kk < 16; ++kk) {
            unsigned off = ((unsigned)(kk * 64 + khi * 16)) ^ swz;
            bf16x8 af = *(const bf16x8*)(xrow_p + off);
            if (kk & 1) acc_x1 = __builtin_amdgcn_mfma_f32_16x16x32_bf16(af, wfrag[kk], acc_x1, 0, 0, 0);
            else        acc_x0 = __builtin_amdgcn_mfma_f32_16x16x32_bf16(af, wfrag[kk], acc_x0, 0, 0, 0);
        }
    }
    __syncthreads();

    #pragma unroll 1
    for (int t = 0; t < T_STEPS; ++t) {
        // ---- P1: h-MFMA (h_{t-1} in hslot[t&1]); acc seeded with x-part(t) ----
        const unsigned hbase = 16384u + (unsigned)(t & 1) * 16384u;
        f32x4 acc0 = acc_x0;
        f32x4 acc1 = acc_x1;
        const unsigned char* hrow_p = smem + hbase + (size_t)ln15 * 1024;
        #pragma unroll
        for (int kk = 16; kk < 32; ++kk) {
            unsigned off = ((unsigned)((kk - 16) * 64 + khi * 16)) ^ swz;
            bf16x8 af = *(const bf16x8*)(hrow_p + off);
            if (kk & 1) acc1 = __builtin_amdgcn_mfma_f32_16x16x32_bf16(af, wfrag[kk], acc1, 0, 0, 0);
            else        acc0 = __builtin_amdgcn_mfma_f32_16x16x32_bf16(af, wfrag[kk], acc0, 0, 0, 0);
        }
        f32x4 accs = acc0 + acc1;

        // ---- P2: activation + intra-wave gate exchange + cell update ----
        float hR[4];
        const int srcbase = lane & 0x3C;
        #pragma unroll
        for (int R = 0; R < 4; ++R) {
            float x = accs[R];
            bool isg = (gown == 2);
            float e = __expf(isg ? 2.f * x : -x);
            float r = __builtin_amdgcn_rcpf(1.f + e);
            float a = isg ? 1.f - 2.f * r : r;
            float vi = __shfl(a, srcbase + 0);
            float vf = __shfl(a, srcbase + 1);
            float vg = __shfl(a, srcbase + 2);
            float vo = __shfl(a, srcbase + 3);
            float c = vf * creg[R] + vi * vg;
            creg[R] = c;
            hR[R] = vo * tanh_fast(c);
        }

        if (t == T_STEPS - 1) {
            // ---- epilogue: out[T-1], hT, cT ----
            #pragma unroll
            for (int R = 0; R < 4; ++R) {
                if (gown == R) {
                    size_t o2 = (size_t)(bt * BT + khi * 4 + R) * HID + jcol;
                    out[(size_t)t * BH + o2] = hR[R];
                    size_t base = (size_t)T_STEPS * BH;
                    out[base + o2] = hR[R];
                    out[base + BH + o2] = creg[R];
                }
            }
        } else {
            // ---- P3: publish h_t (self-validating, MALL-coherent) + out store ----
            #pragma unroll
            for (int R = 0; R < 4; ++R) {
                if (gown == R) {
                    unsigned w = ((unsigned)(t + 1) << 16) | (unsigned)f2bf(hR[R]);
                    unsigned* hp = hseq + (size_t)(t & 1) * BH
                                        + (size_t)(bt * BT + khi * 4 + R) * HID + jcol;
                    asm volatile("global_store_dword %0, %1, off sc0 sc1"
                                 :: "v"(hp), "v"(w) : "memory");
                }
            }
            #pragma unroll
            for (int R = 0; R < 4; ++R) {
                if (gown == R)
                    out[(size_t)t * BH + (size_t)(bt * BT + khi * 4 + R) * HID + jcol] = hR[R];
            }

            // ---- P4: stage x_{t+1} (xr) -> xslot ----
            #pragma unroll
            for (int i = 0; i < 8; ++i) {
                int row = xrow0 + 2 * i;
                unsigned off = ((unsigned)(xcol4 * 8)) ^ ((unsigned)((row & 7) << 4));
                *(ushort4*)(smem + (size_t)row * 1024 + off) = pack4(xr[i]);
            }
            // ---- P5: prefetch x_{t+2} (in flight through B1 and x-MFMA) ----
            {
                int tn = (t + 2) & (T_STEPS - 1);
                #pragma unroll
                for (int i = 0; i < 8; ++i)
                    xr[i] = *(const float4*)(xin + (size_t)tn * (BATCH * IN)
                                                 + (size_t)(bt * BT + xrow0 + 2 * i) * IN + xcol4 * 4);
            }

            // ---- B1: make xslot visible across waves ----
            asm volatile("s_waitcnt lgkmcnt(0)" ::: "memory");
            __builtin_amdgcn_s_barrier();

            // ---- P6: x-MFMA for step t+1 (in the publish->poll shadow) ----
            acc_x0 = f32x4{biasv, biasv, biasv, biasv};
            acc_x1 = f32x4{0.f, 0.f, 0.f, 0.f};
            {
                const unsigned char* xrow_p = smem + (size_t)ln15 * 1024;
                #pragma unroll
                for (int kk = 0; kk < 16; ++kk) {
                    unsigned off = ((unsigned)(kk * 64 + khi * 16)) ^ swz;
                    bf16x8 af = *(const bf16x8*)(xrow_p + off);
                    if (kk & 1) acc_x1 = __builtin_amdgcn_mfma_f32_16x16x32_bf16(af, wfrag[kk], acc_x1, 0, 0, 0);
                    else        acc_x0 = __builtin_amdgcn_mfma_f32_16x16x32_bf16(af, wfrag[kk], acc_x0, 0, 0, 0);
                }
            }

            // ---- P7: poll h_t tile (batched self-validating sweeps) ----
            const unsigned* pp = hseq + (size_t)(t & 1) * BH
                                      + (size_t)(bt * BT + prow) * HID + ln15 * 4;
            const unsigned tgtw = (unsigned)(t + 1) << 16;
            u32x4 hv0, hv1, hv2, hv3, hv4, hv5, hv6, hv7;
            for (;;) {
                asm volatile(
                    "global_load_dwordx4 %0, %8, off offset:0 sc0 sc1\n\t"
                    "global_load_dwordx4 %1, %8, off offset:256 sc0 sc1\n\t"
                    "global_load_dwordx4 %2, %8, off offset:512 sc0 sc1\n\t"
                    "global_load_dwordx4 %3, %8, off offset:768 sc0 sc1\n\t"
                    "global_load_dwordx4 %4, %8, off offset:1024 sc0 sc1\n\t"
                    "global_load_dwordx4 %5, %8, off offset:1280 sc0 sc1\n\t"
                    "global_load_dwordx4 %6, %8, off offset:1536 sc0 sc1\n\t"
                    "global_load_dwordx4 %7, %8, off offset:1792 sc0 sc1\n\t"
                    "s_waitcnt vmcnt(0)"
                    : "=&v"(hv0), "=&v"(hv1), "=&v"(hv2), "=&v"(hv3),
                      "=&v"(hv4), "=&v"(hv5), "=&v"(hv6), "=&v"(hv7)
                    : "v"(pp) : "memory");
                bool ok = vld4(hv0, tgtw) & vld4(hv1, tgtw) & vld4(hv2, tgtw) & vld4(hv3, tgtw)
                        & vld4(hv4, tgtw) & vld4(hv5, tgtw) & vld4(hv6, tgtw) & vld4(hv7, tgtw);
                if (__ballot(ok) == ~0ull) break;
            }

            // ---- P8: pack polled h_t -> hslot[(t+1)&1] ----
            {
                unsigned hnb = 16384u + (unsigned)((t + 1) & 1) * 16384u;
                unsigned wbase = hnb + (unsigned)prow * 1024u;
                const u32x4 hv[8] = {hv0, hv1, hv2, hv3, hv4, hv5, hv6, hv7};
                #pragma unroll
                for (int q = 0; q < 8; ++q) {
                    uint2 pk;
                    pk.x = (hv[q][0] & 0xFFFFu) | (hv[q][1] << 16);
                    pk.y = (hv[q][2] & 0xFFFFu) | (hv[q][3] << 16);
                    unsigned off = ((unsigned)(q * 128 + ln15 * 8)) ^ rsw;
                    *(uint2*)(smem + wbase + off) = pk;
                }
            }

            // ---- B2: h slot visible; next iter may overwrite xslot after this ----
            asm volatile("s_waitcnt lgkmcnt(0)" ::: "memory");
            __builtin_amdgcn_s_barrier();
        }
    }
}

extern "C" void kernel_launch(void* const* d_in, const int* in_sizes, int n_in,
                              void* d_out, int out_size, void* d_ws, size_t ws_size,
                              hipStream_t stream) {
    const float* input = (const float*)d_in[0];
    const float* h0    = (const float*)d_in[1];
    const float* c0    = (const float*)d_in[2];
    const float* W_ih  = (const float*)d_in[3];
    const float* W_hh  = (const float*)d_in[4];
    const float* b_ih  = (const float*)d_in[5];
    const float* b_hh  = (const float*)d_in[6];
    float* out = (float*)d_out;

    char* ws = (char*)d_ws;
    unsigned* hseq = (unsigned*)ws;                            // 2*128*512*4 = 512 KB
    float*    bias = (float*)(ws + 512 * 1024);                // 8 KB
    unsigned short* Wc = (unsigned short*)(ws + 512 * 1024 + 16 * 1024);  // 4 MB

    hipMemsetAsync(hseq, 0, 2 * BH * sizeof(unsigned), stream);
    prep_kernel<<<2048, 256, 0, stream>>>(W_ih, W_hh, b_ih, b_hh, Wc, bias);
    lstm_kernel<<<NBT * NJT, 256, 0, stream>>>(input, h0, c0, Wc, bias, out, hseq);
}

// Round 12
// 1917.058 us; speedup vs baseline: 3.8841x; 1.2612x over previous
//
#include <hip/hip_runtime.h>
#include <hip/hip_bf16.h>

#define T_STEPS 512
#define BATCH   128
#define IN      512
#define HID     512
#define KTOT    1024   // IN + HID fused
#define BT      16     // batch rows per block
#define JT      32     // hidden cols per block
#define NBT     8      // batch groups
#define NJT     16     // blocks per group
#define BH      (BATCH * HID)

typedef __attribute__((ext_vector_type(8))) short bf16x8;
typedef __attribute__((ext_vector_type(4))) float f32x4;
typedef __attribute__((ext_vector_type(4))) unsigned int u32x4;

static __device__ __forceinline__ unsigned short f2bf(float f) {
    unsigned u = __float_as_uint(f);
    unsigned r = (u + 0x7FFFu + ((u >> 16) & 1u)) >> 16;   // RNE, finite inputs only
    return (unsigned short)r;
}
static __device__ __forceinline__ ushort4 pack4(float4 v) {
    ushort4 b4;
    b4.x = f2bf(v.x); b4.y = f2bf(v.y); b4.z = f2bf(v.z); b4.w = f2bf(v.w);
    return b4;
}
static __device__ __forceinline__ float tanh_fast(float x) {
    return 1.f - 2.f * __builtin_amdgcn_rcpf(1.f + __expf(2.f * x));
}
static __device__ __forceinline__ bool vld4(u32x4 v, unsigned tgtw) {
    return ((v[0] & 0xFFFF0000u) == tgtw) & ((v[1] & 0xFFFF0000u) == tgtw) &
           ((v[2] & 0xFFFF0000u) == tgtw) & ((v[3] & 0xFFFF0000u) == tgtw);
}

// ---- prep: fuse W_ih|W_hh into bf16 [2048][1024], bias = b_ih + b_hh ----
__global__ void prep_kernel(const float* __restrict__ W_ih, const float* __restrict__ W_hh,
                            const float* __restrict__ b_ih, const float* __restrict__ b_hh,
                            unsigned short* __restrict__ Wc, float* __restrict__ bias) {
    int idx = blockIdx.x * blockDim.x + threadIdx.x;   // 0 .. 2048*256-1 float4 granules
    int row = idx >> 8;
    int kq  = idx & 255;
    const float* src = (kq < 128) ? (W_ih + (size_t)row * IN + kq * 4)
                                  : (W_hh + (size_t)row * HID + (kq - 128) * 4);
    float4 v = *(const float4*)src;
    *(ushort4*)(Wc + (size_t)row * KTOT + kq * 4) = pack4(v);
    if (idx < 4 * HID) bias[idx] = b_ih[idx] + b_hh[idx];
}

// ---- persistent LSTM kernel: 512 threads, 8 waves, 16 batch x 32 hidden per block ----
__global__ __launch_bounds__(512, 2) void lstm_kernel(
    const float* __restrict__ xin, const float* __restrict__ h0,
    const float* __restrict__ c0, const unsigned short* __restrict__ Wc,
    const float* __restrict__ bias, float* __restrict__ out,
    unsigned* __restrict__ hseq)   // [2][BATCH][HID] u32: (seq<<16)|bf16(h)
{
    const int tid  = threadIdx.x;
    const int bid  = blockIdx.x;
    const int bt   = bid & 7;        // batch group
    const int jt   = bid >> 3;       // j tile 0..15 (32 cols each)
    const int wv   = tid >> 6;       // wave id 0..7
    const int lane = tid & 63;
    const int ln15 = lane & 15;
    const int khi  = lane >> 4;

    // x slot [0,16K); h slots [16K,32K),[32K,48K)
    __shared__ __align__(16) unsigned char smem[49152];

    const int gown = ln15 & 3;              // lane's gate (0=i,1=f,2=g,3=o)
    const int jj   = ln15 >> 2;             // j sub-index
    const int jcol = jt * JT + wv * 4 + jj; // global hidden unit
    const int wrow_idx = gown * HID + jcol;

    // B-fragments (gate-interleaved columns) in VGPRs
    bf16x8 wfrag[32];
    {
        const unsigned short* wrow = Wc + (size_t)wrow_idx * KTOT;
        #pragma unroll
        for (int kk = 0; kk < 32; ++kk)
            wfrag[kk] = *(const bf16x8*)(wrow + kk * 32 + khi * 8);
    }
    const float biasv = bias[wrow_idx];

    // cell state: creg[R] = c(b = khi*4+R, jcol), 4x redundant across gate lanes
    float creg[4];
    #pragma unroll
    for (int R = 0; R < 4; ++R)
        creg[R] = c0[(size_t)(bt * BT + khi * 4 + R) * HID + jcol];

    const unsigned swz = (unsigned)((ln15 & 7) << 4);
    const int xrow0 = tid >> 7;          // 0..3
    const int xcol4 = tid & 127;         // float4 granule within 512-wide fp32 row

    // poll/pack mapping: quarter q = wv*4+khi (0..31); row = q>>1, half = q&1 (256 cols)
    const int q     = wv * 4 + khi;
    const int prow  = q >> 1;
    const int qh    = q & 1;
    const unsigned rsw = (unsigned)((prow & 7) << 4);

    // ---- prologue: stage x0 -> xslot, h0 -> hslot0; prefetch x1; x-MFMA(step0) ----
    #pragma unroll
    for (int i = 0; i < 4; ++i) {
        int row = xrow0 + 4 * i;
        unsigned off = ((unsigned)(xcol4 * 8)) ^ ((unsigned)((row & 7) << 4));
        float4 vx = *(const float4*)(xin + (size_t)(bt * BT + row) * IN + xcol4 * 4);
        *(ushort4*)(smem + (size_t)row * 1024 + off) = pack4(vx);
        float4 vh = *(const float4*)(h0 + (size_t)(bt * BT + row) * HID + xcol4 * 4);
        *(ushort4*)(smem + 16384 + (size_t)row * 1024 + off) = pack4(vh);
    }
    float4 xr[4];
    #pragma unroll
    for (int i = 0; i < 4; ++i)
        xr[i] = *(const float4*)(xin + (size_t)1 * (BATCH * IN)
                                     + (size_t)(bt * BT + xrow0 + 4 * i) * IN + xcol4 * 4);
    __syncthreads();

    f32x4 acc_x0 = {biasv, biasv, biasv, biasv};
    f32x4 acc_x1 = {0.f, 0.f, 0.f, 0.f};
    {
        const unsigned char* xrow_p = smem + (size_t)ln15 * 1024;
        #pragma unroll
        for (int kk = 0; kk < 16; ++kk) {
            unsigned off = ((unsigned)(kk * 64 + khi * 16)) ^ swz;
            bf16x8 af = *(const bf16x8*)(xrow_p + off);
            if (kk & 1) acc_x1 = __builtin_amdgcn_mfma_f32_16x16x32_bf16(af, wfrag[kk], acc_x1, 0, 0, 0);
            else        acc_x0 = __builtin_amdgcn_mfma_f32_16x16x32_bf16(af, wfrag[kk], acc_x0, 0, 0, 0);
        }
    }
    __syncthreads();

    #pragma unroll 1
    for (int t = 0; t < T_STEPS; ++t) {
        // ---- P1: h-MFMA (h_{t-1} in hslot[t&1]); acc seeded with x-part(t) ----
        const unsigned hbase = 16384u + (unsigned)(t & 1) * 16384u;
        f32x4 acc0 = acc_x0;
        f32x4 acc1 = acc_x1;
        const unsigned char* hrow_p = smem + hbase + (size_t)ln15 * 1024;
        #pragma unroll
        for (int kk = 16; kk < 32; ++kk) {
            unsigned off = ((unsigned)((kk - 16) * 64 + khi * 16)) ^ swz;
            bf16x8 af = *(const bf16x8*)(hrow_p + off);
            if (kk & 1) acc1 = __builtin_amdgcn_mfma_f32_16x16x32_bf16(af, wfrag[kk], acc1, 0, 0, 0);
            else        acc0 = __builtin_amdgcn_mfma_f32_16x16x32_bf16(af, wfrag[kk], acc0, 0, 0, 0);
        }
        f32x4 accs = acc0 + acc1;

        // ---- P2: activation + intra-wave gate exchange + cell update ----
        float hR[4];
        const int srcbase = lane & 0x3C;
        #pragma unroll
        for (int R = 0; R < 4; ++R) {
            float x = accs[R];
            bool isg = (gown == 2);
            float e = __expf(isg ? 2.f * x : -x);
            float r = __builtin_amdgcn_rcpf(1.f + e);
            float a = isg ? 1.f - 2.f * r : r;
            float vi = __shfl(a, srcbase + 0);
            float vf = __shfl(a, srcbase + 1);
            float vg = __shfl(a, srcbase + 2);
            float vo = __shfl(a, srcbase + 3);
            float c = vf * creg[R] + vi * vg;
            creg[R] = c;
            hR[R] = vo * tanh_fast(c);
        }

        if (t == T_STEPS - 1) {
            // ---- epilogue: out[T-1], hT, cT ----
            #pragma unroll
            for (int R = 0; R < 4; ++R) {
                if (gown == R) {
                    size_t o2 = (size_t)(bt * BT + khi * 4 + R) * HID + jcol;
                    out[(size_t)t * BH + o2] = hR[R];
                    size_t base = (size_t)T_STEPS * BH;
                    out[base + o2] = hR[R];
                    out[base + BH + o2] = creg[R];
                }
            }
        } else {
            // ---- P3: publish h_t (self-validating, MALL-coherent) + out store ----
            #pragma unroll
            for (int R = 0; R < 4; ++R) {
                if (gown == R) {
                    unsigned w = ((unsigned)(t + 1) << 16) | (unsigned)f2bf(hR[R]);
                    unsigned* hp = hseq + (size_t)(t & 1) * BH
                                        + (size_t)(bt * BT + khi * 4 + R) * HID + jcol;
                    asm volatile("global_store_dword %0, %1, off sc0 sc1"
                                 :: "v"(hp), "v"(w) : "memory");
                }
            }
            #pragma unroll
            for (int R = 0; R < 4; ++R) {
                if (gown == R)
                    out[(size_t)t * BH + (size_t)(bt * BT + khi * 4 + R) * HID + jcol] = hR[R];
            }

            // ---- P4: stage x_{t+1} (xr) -> xslot ----
            #pragma unroll
            for (int i = 0; i < 4; ++i) {
                int row = xrow0 + 4 * i;
                unsigned off = ((unsigned)(xcol4 * 8)) ^ ((unsigned)((row & 7) << 4));
                *(ushort4*)(smem + (size_t)row * 1024 + off) = pack4(xr[i]);
            }

            // ---- B1: make xslot visible across waves ----
            asm volatile("s_waitcnt lgkmcnt(0)" ::: "memory");
            __builtin_amdgcn_s_barrier();

            // ---- P5: issue first poll sweep NOW (flies during x-MFMA) ----
            const unsigned* pp = hseq + (size_t)(t & 1) * BH
                                      + (size_t)(bt * BT + prow) * HID + qh * 256 + ln15 * 4;
            const unsigned tgtw = (unsigned)(t + 1) << 16;
            u32x4 hv0, hv1, hv2, hv3;
            asm volatile(
                "global_load_dwordx4 %0, %4, off offset:0 sc0 sc1\n\t"
                "global_load_dwordx4 %1, %4, off offset:256 sc0 sc1\n\t"
                "global_load_dwordx4 %2, %4, off offset:512 sc0 sc1\n\t"
                "global_load_dwordx4 %3, %4, off offset:768 sc0 sc1"
                : "=&v"(hv0), "=&v"(hv1), "=&v"(hv2), "=&v"(hv3)
                : "v"(pp) : "memory");

            // ---- P6: prefetch x_{t+2} (issued after sweeps; stays in flight) ----
            {
                int tn = (t + 2) & (T_STEPS - 1);
                #pragma unroll
                for (int i = 0; i < 4; ++i)
                    xr[i] = *(const float4*)(xin + (size_t)tn * (BATCH * IN)
                                                 + (size_t)(bt * BT + xrow0 + 4 * i) * IN + xcol4 * 4);
            }

            // ---- P7: x-MFMA for step t+1 (sweep flight hides under this) ----
            acc_x0 = f32x4{biasv, biasv, biasv, biasv};
            acc_x1 = f32x4{0.f, 0.f, 0.f, 0.f};
            {
                const unsigned char* xrow_p = smem + (size_t)ln15 * 1024;
                #pragma unroll
                for (int kk = 0; kk < 16; ++kk) {
                    unsigned off = ((unsigned)(kk * 64 + khi * 16)) ^ swz;
                    bf16x8 af = *(const bf16x8*)(xrow_p + off);
                    if (kk & 1) acc_x1 = __builtin_amdgcn_mfma_f32_16x16x32_bf16(af, wfrag[kk], acc_x1, 0, 0, 0);
                    else        acc_x0 = __builtin_amdgcn_mfma_f32_16x16x32_bf16(af, wfrag[kk], acc_x0, 0, 0, 0);
                }
            }

            // ---- P8: wait ONLY the 4 sweep loads (x loads keep flying), check, resweep ----
            asm volatile("s_waitcnt vmcnt(4)" ::: "memory");   // sweeps are oldest 4 loads
            __builtin_amdgcn_sched_barrier(0);
            for (;;) {
                bool ok = vld4(hv0, tgtw) & vld4(hv1, tgtw) & vld4(hv2, tgtw) & vld4(hv3, tgtw);
                if (__ballot(ok) == ~0ull) break;
                asm volatile(
                    "global_load_dwordx4 %0, %4, off offset:0 sc0 sc1\n\t"
                    "global_load_dwordx4 %1, %4, off offset:256 sc0 sc1\n\t"
                    "global_load_dwordx4 %2, %4, off offset:512 sc0 sc1\n\t"
                    "global_load_dwordx4 %3, %4, off offset:768 sc0 sc1\n\t"
                    "s_waitcnt vmcnt(0)"
                    : "=&v"(hv0), "=&v"(hv1), "=&v"(hv2), "=&v"(hv3)
                    : "v"(pp) : "memory");
                __builtin_amdgcn_sched_barrier(0);
            }

            // ---- P9: pack polled half-row -> hslot[(t+1)&1] ----
            {
                unsigned hnb = 16384u + (unsigned)((t + 1) & 1) * 16384u;
                unsigned wbase = hnb + (unsigned)prow * 1024u;
                const u32x4 hv[4] = {hv0, hv1, hv2, hv3};
                #pragma unroll
                for (int sq = 0; sq < 4; ++sq) {
                    uint2 pk;
                    pk.x = (hv[sq][0] & 0xFFFFu) | (hv[sq][1] << 16);
                    pk.y = (hv[sq][2] & 0xFFFFu) | (hv[sq][3] << 16);
                    unsigned off = ((unsigned)(qh * 512 + sq * 128 + ln15 * 8)) ^ rsw;
                    *(uint2*)(smem + wbase + off) = pk;
                }
            }

            // ---- B2: h slot visible ----
            asm volatile("s_waitcnt lgkmcnt(0)" ::: "memory");
            __builtin_amdgcn_s_barrier();
        }
    }
}

extern "C" void kernel_launch(void* const* d_in, const int* in_sizes, int n_in,
                              void* d_out, int out_size, void* d_ws, size_t ws_size,
                              hipStream_t stream) {
    const float* input = (const float*)d_in[0];
    const float* h0    = (const float*)d_in[1];
    const float* c0    = (const float*)d_in[2];
    const float* W_ih  = (const float*)d_in[3];
    const float* W_hh  = (const float*)d_in[4];
    const float* b_ih  = (const float*)d_in[5];
    const float* b_hh  = (const float*)d_in[6];
    float* out = (float*)d_out;

    char* ws = (char*)d_ws;
    unsigned* hseq = (unsigned*)ws;                            // 2*128*512*4 = 512 KB
    float*    bias = (float*)(ws + 512 * 1024);                // 8 KB
    unsigned short* Wc = (unsigned short*)(ws + 512 * 1024 + 16 * 1024);  // 4 MB

    hipMemsetAsync(hseq, 0, 2 * BH * sizeof(unsigned), stream);
    prep_kernel<<<2048, 256, 0, stream>>>(W_ih, W_hh, b_ih, b_hh, Wc, bias);
    lstm_kernel<<<NBT * NJT, 512, 0, stream>>>(input, h0, c0, Wc, bias, out, hseq);
}